// Round 3
// baseline (422.524 us; speedup 1.0000x reference)
//
#include <hip/hip_runtime.h>
#include <hip/hip_bf16.h>

typedef __bf16 bf16;
typedef bf16 bf16x2 __attribute__((ext_vector_type(2)));
typedef bf16 bf16x4 __attribute__((ext_vector_type(4)));
typedef bf16 bf16x8 __attribute__((ext_vector_type(8)));
typedef float floatx4 __attribute__((ext_vector_type(4)));

#define MFMA_BF16(a, b, c) __builtin_amdgcn_mfma_f32_16x16x32_bf16((a), (b), (c), 0, 0, 0)

// ---------------------------------------------------------------------------
// fp32 -> bf16 convert for BOTH x and ctx in one launch (8 els/thread).
// ---------------------------------------------------------------------------
__global__ __launch_bounds__(256) void cvt2_kernel(const float* __restrict__ x,
                                                   const float* __restrict__ ctx,
                                                   bf16* __restrict__ xb,
                                                   bf16* __restrict__ cb) {
    int idx = blockIdx.x * 256 + threadIdx.x;   // 0..1048575
    const float* in;
    bf16* out;
    int i;
    if (idx < 524288) { in = x; out = xb; i = idx; }
    else              { in = ctx; out = cb; i = idx - 524288; }
    const float* src = in + (size_t)i * 8;
    float4 f0 = *(const float4*)src;
    float4 f1 = *(const float4*)(src + 4);
    bf16x8 v = {(bf16)f0.x, (bf16)f0.y, (bf16)f0.z, (bf16)f0.w,
                (bf16)f1.x, (bf16)f1.y, (bf16)f1.z, (bf16)f1.w};
    *(bf16x8*)(out + (size_t)i * 8) = v;
}

// ---------------------------------------------------------------------------
// fp32 [1024][C] -> bf16 [C][1024] transpose for BOTH Wq (z=0) and Wkv (z=1).
// ---------------------------------------------------------------------------
__global__ __launch_bounds__(256) void trans2_kernel(const float* __restrict__ Wq,
                                                     const float* __restrict__ Wkv,
                                                     bf16* __restrict__ WqT,
                                                     bf16* __restrict__ WkvT) {
    const int z = blockIdx.z;
    if (z == 0 && blockIdx.x >= 32) return;
    const float* in = z ? Wkv : Wq;
    bf16* out = z ? WkvT : WqT;
    const int C = z ? 2048 : 1024, R = 1024;
    __shared__ float tile[32][33];
    const int t = threadIdx.x;
    const int r0 = blockIdx.y * 32, c0 = blockIdx.x * 32;
    int r = t >> 3, c4 = (t & 7) * 4;
    float4 v = *(const float4*)&in[(size_t)(r0 + r) * C + c0 + c4];
    tile[r][c4 + 0] = v.x; tile[r][c4 + 1] = v.y;
    tile[r][c4 + 2] = v.z; tile[r][c4 + 3] = v.w;
    __syncthreads();
    int rp = t >> 3, cp = (t & 7) * 4;
    bf16x4 w = {(bf16)tile[cp + 0][rp], (bf16)tile[cp + 1][rp],
                (bf16)tile[cp + 2][rp], (bf16)tile[cp + 3][rp]};
    *(bf16x4*)&out[(size_t)(c0 + rp) * R + r0 + cp] = w;
}

// ---------------------------------------------------------------------------
// Merged 128x128 GEMM: blockIdx.x<8 -> Q = xb @ WqT^T; else KV = cb @ WkvT^T.
// KV epilogue: n<1024 -> Kb[m][n]; n>=1024 -> Vt[b][h][d][j] directly (bf16x4,
// the 4 acc regs per (mt,nt) are consecutive j).
// ---------------------------------------------------------------------------
__global__ __launch_bounds__(256) void gemm_all(const bf16* __restrict__ xb,
                                                const bf16* __restrict__ cb,
                                                const bf16* __restrict__ WqT,
                                                const bf16* __restrict__ WkvT,
                                                bf16* __restrict__ Qb,
                                                bf16* __restrict__ Kb,
                                                bf16* __restrict__ Vt) {
    __shared__ bf16 As[128 * 40];
    __shared__ bf16 Bs[128 * 40];
    const bool isQ = blockIdx.x < 8;
    const bf16* A = isQ ? xb : cb;
    const bf16* B = isQ ? WqT : WkvT;
    const int t = threadIdx.x;
    const int wv = t >> 6, lane = t & 63, quad = lane >> 4, l15 = lane & 15;
    const int wr = wv >> 1, wc = wv & 1;
    const int m0 = blockIdx.y * 128;
    const int n0 = (isQ ? blockIdx.x : blockIdx.x - 8) * 128;
    const int ra = t >> 1, kc = (t & 1) * 16;

    floatx4 acc[4][4] = {};

    for (int k0 = 0; k0 < 1024; k0 += 32) {
        bf16x8 a0 = *(const bf16x8*)&A[(size_t)(m0 + ra) * 1024 + k0 + kc];
        bf16x8 a1 = *(const bf16x8*)&A[(size_t)(m0 + ra) * 1024 + k0 + kc + 8];
        bf16x8 b0 = *(const bf16x8*)&B[(size_t)(n0 + ra) * 1024 + k0 + kc];
        bf16x8 b1 = *(const bf16x8*)&B[(size_t)(n0 + ra) * 1024 + k0 + kc + 8];
        __syncthreads();
        *(bf16x8*)&As[ra * 40 + kc] = a0;
        *(bf16x8*)&As[ra * 40 + kc + 8] = a1;
        *(bf16x8*)&Bs[ra * 40 + kc] = b0;
        *(bf16x8*)&Bs[ra * 40 + kc + 8] = b1;
        __syncthreads();
        bf16x8 af[4], bfr[4];
#pragma unroll
        for (int mt = 0; mt < 4; ++mt)
            af[mt] = *(bf16x8*)&As[(wr * 64 + mt * 16 + l15) * 40 + quad * 8];
#pragma unroll
        for (int nt = 0; nt < 4; ++nt)
            bfr[nt] = *(bf16x8*)&Bs[(wc * 64 + nt * 16 + l15) * 40 + quad * 8];
#pragma unroll
        for (int mt = 0; mt < 4; ++mt)
#pragma unroll
            for (int nt = 0; nt < 4; ++nt)
                acc[mt][nt] = MFMA_BF16(af[mt], bfr[nt], acc[mt][nt]);
    }
#pragma unroll
    for (int mt = 0; mt < 4; ++mt)
#pragma unroll
        for (int nt = 0; nt < 4; ++nt) {
            int mb = m0 + wr * 64 + mt * 16 + quad * 4;  // m for r=0 (4-aligned run)
            int n = n0 + wc * 64 + nt * 16 + l15;
            if (isQ) {
#pragma unroll
                for (int r = 0; r < 4; ++r)
                    Qb[(size_t)(mb + r) * 1024 + n] = (bf16)acc[mt][nt][r];
            } else if (n < 1024) {
#pragma unroll
                for (int r = 0; r < 4; ++r)
                    Kb[(size_t)(mb + r) * 1024 + n] = (bf16)acc[mt][nt][r];
            } else {
                int nn = n - 1024, h = nn >> 6, d = nn & 63;
                int bb = mb >> 10, j = mb & 1023;
                bf16x4 v4 = {(bf16)acc[mt][nt][0], (bf16)acc[mt][nt][1],
                             (bf16)acc[mt][nt][2], (bf16)acc[mt][nt][3]};
                *(bf16x4*)&Vt[(size_t)((bb * 16 + h) * 64 + d) * 1024 + j] = v4;
            }
        }
}

// ---------------------------------------------------------------------------
// Softmax denominators: L[b][h][i] = sum_j exp(q.k*scale).
// grid (i32=32, b=4, jsplit=8), 256 thr = 4 waves, 4 heads/wave, 4 blk/CU.
// ---------------------------------------------------------------------------
__global__ __launch_bounds__(256, 4) void denom_kernel(const bf16* __restrict__ Qb,
                                                       const bf16* __restrict__ Kb,
                                                       float* __restrict__ L) {
    const int t = threadIdx.x;
    const int wv = t >> 6, lane = t & 63, quad = lane >> 4, l15 = lane & 15;
    const int i0 = blockIdx.x * 32, b = blockIdx.y, jz = blockIdx.z;
    const float scale = 0.125f;

    bf16x8 qa[4][2][2];
#pragma unroll
    for (int hh = 0; hh < 4; ++hh)
#pragma unroll
        for (int it = 0; it < 2; ++it) {
            const bf16* qp = Qb + (size_t)(b * 1024 + i0 + it * 16 + l15) * 1024 +
                             (wv * 4 + hh) * 64 + quad * 8;
            qa[hh][it][0] = *(const bf16x8*)qp;
            qa[hh][it][1] = *(const bf16x8*)(qp + 32);
        }
    floatx4 se[4][2] = {};
    const bf16* Kbase = Kb + (size_t)b * 1024 * 1024;

    for (int jt = 0; jt < 8; ++jt) {
        int j = jz * 128 + jt * 16 + l15;
#pragma unroll
        for (int hh = 0; hh < 4; ++hh) {
            const bf16* kp = Kbase + (size_t)j * 1024 + (wv * 4 + hh) * 64 + quad * 8;
            bf16x8 k0 = *(const bf16x8*)kp;
            bf16x8 k1 = *(const bf16x8*)(kp + 32);
#pragma unroll
            for (int it = 0; it < 2; ++it) {
                floatx4 c = {0.f, 0.f, 0.f, 0.f};
                c = MFMA_BF16(qa[hh][it][0], k0, c);
                c = MFMA_BF16(qa[hh][it][1], k1, c);
#pragma unroll
                for (int r = 0; r < 4; ++r) se[hh][it][r] += __expf(c[r] * scale);
            }
        }
    }
#pragma unroll
    for (int hh = 0; hh < 4; ++hh)
#pragma unroll
        for (int it = 0; it < 2; ++it)
#pragma unroll
            for (int r = 0; r < 4; ++r) {
                float s = se[hh][it][r];
                s += __shfl_xor(s, 1); s += __shfl_xor(s, 2);
                s += __shfl_xor(s, 4); s += __shfl_xor(s, 8);
                if (l15 == 0)
                    atomicAdd(&L[(size_t)(b * 16 + wv * 4 + hh) * 1024 + i0 + it * 16 +
                                 quad * 4 + r], s);
            }
}

// ---------------------------------------------------------------------------
// Main fused attention. grid (i16=64, b=4, jsplit=2), 512 thr = 8 waves,
// 2 heads/wave, 64-wide j tiles (8 iters, 2 barriers each).
// (a) S (MFMA) -> w=exp*invl -> Buf1[point][h]
// (b) centered-Wt mix (MFMA, C[g][point]) + LN over g (2 shuffles) -> Buf2
// (c) PV (MFMA, Vt B-frags from global). Partials atomicAdd'ed to out.
// ---------------------------------------------------------------------------
__global__ __launch_bounds__(512, 4) void attn_kernel(const bf16* __restrict__ Qb,
                                                      const bf16* __restrict__ Kb,
                                                      const bf16* __restrict__ Vt,
                                                      const float* __restrict__ L,
                                                      const float* __restrict__ Wt,
                                                      const float* __restrict__ gamma,
                                                      const float* __restrict__ beta,
                                                      float* __restrict__ out) {
    __shared__ bf16 Buf1[1024 * 20];       // [point p=i*64+jl][16 h + 4 pad] = 40 KB
    __shared__ bf16 Buf2[16 * 1160];       // [g][i*72 + jl], 36.25 KB
    __shared__ __align__(16) bf16 Zbuf[8]; // zero region for mix k>=16

    const int t = threadIdx.x;
    const int wv = t >> 6, lane = t & 63, quad = lane >> 4, l15 = lane & 15;
    const int i0 = blockIdx.x * 16, b = blockIdx.y, jz = blockIdx.z;
    const float scale = 0.125f;

    if (t < 8) Zbuf[t] = (bf16)0.f;

    // A-frag of centered Wt^T: a_wt[jj] = Wt_c[k=quad*8+jj][g=l15], 0 for k>=16.
    bf16x8 a_wt;
#pragma unroll
    for (int jj = 0; jj < 8; ++jj) {
        int k = quad * 8 + jj;
        float v = 0.f;
        if (k < 16) {
            float s = 0.f;
            for (int g = 0; g < 16; ++g) s += Wt[k * 16 + g];
            v = Wt[k * 16 + l15] - s * 0.0625f;
        }
        a_wt[jj] = (bf16)v;
    }
    float gq[4], bq[4];
#pragma unroll
    for (int r = 0; r < 4; ++r) { gq[r] = gamma[quad * 4 + r]; bq[r] = beta[quad * 4 + r]; }

    bf16x8 qa[2][2];
    float invl[2][4];
#pragma unroll
    for (int hh = 0; hh < 2; ++hh) {
        int h = wv * 2 + hh;
        const bf16* qp = Qb + (size_t)(b * 1024 + i0 + l15) * 1024 + h * 64 + quad * 8;
        qa[hh][0] = *(const bf16x8*)qp;
        qa[hh][1] = *(const bf16x8*)(qp + 32);
#pragma unroll
        for (int r = 0; r < 4; ++r)
            invl[hh][r] = 1.f / L[(size_t)(b * 16 + h) * 1024 + i0 + quad * 4 + r];
    }

    const bf16* Kbase = Kb + (size_t)b * 1024 * 1024;
    const bf16* Vbase = Vt + (size_t)b * 16 * 64 * 1024;
    floatx4 o[2][4] = {};

    for (int jt = 0; jt < 8; ++jt) {
        const int j0 = jz * 512 + jt * 64;
        // (a) S -> w -> Buf1 (packed bf16x2 for the wave's head pair)
#pragma unroll
        for (int ns = 0; ns < 4; ++ns) {
            floatx4 cw[2];
#pragma unroll
            for (int hh = 0; hh < 2; ++hh) {
                int h = wv * 2 + hh;
                const bf16* kp = Kbase + (size_t)(j0 + ns * 16 + l15) * 1024 + h * 64 + quad * 8;
                floatx4 c = {0.f, 0.f, 0.f, 0.f};
                c = MFMA_BF16(qa[hh][0], *(const bf16x8*)kp, c);
                c = MFMA_BF16(qa[hh][1], *(const bf16x8*)(kp + 32), c);
                cw[hh] = c;
            }
#pragma unroll
            for (int r = 0; r < 4; ++r) {
                bf16x2 pk = {(bf16)(__expf(cw[0][r] * scale) * invl[0][r]),
                             (bf16)(__expf(cw[1][r] * scale) * invl[1][r])};
                *(bf16x2*)&Buf1[((quad * 4 + r) * 64 + ns * 16 + l15) * 20 + wv * 2] = pk;
            }
        }
        __syncthreads();
        // (b) mix (C[g][point]) + LN over g (mean exactly 0 by centering)
#pragma unroll
        for (int grp = 0; grp < 8; ++grp) {
            int gi = wv * 8 + grp, ig = gi >> 2, jb = (gi & 3) * 16;
            int p = ig * 64 + jb + l15;
            const bf16* src = (quad < 2) ? &Buf1[p * 20 + quad * 8] : Zbuf;
            floatx4 c = {0.f, 0.f, 0.f, 0.f};
            c = MFMA_BF16(a_wt, *(const bf16x8*)src, c);
            float s2 = c[0] * c[0] + c[1] * c[1] + c[2] * c[2] + c[3] * c[3];
            s2 += __shfl_xor(s2, 16);
            s2 += __shfl_xor(s2, 32);
            float rs = rsqrtf(s2 * 0.0625f + 1e-5f);
#pragma unroll
            for (int r = 0; r < 4; ++r) {
                float w2 = c[r] * rs * gq[r] + bq[r];
                Buf2[(quad * 4 + r) * 1160 + ig * 72 + jb + l15] = (bf16)w2;
            }
        }
        __syncthreads();
        // (c) PV: O[i][d] += w2[i][jl] * V[jl][d], 64-wide j in two 32 chunks
#pragma unroll
        for (int hh = 0; hh < 2; ++hh) {
            int g = wv * 2 + hh;
#pragma unroll
            for (int sub = 0; sub < 2; ++sub) {
                bf16x8 a = *(bf16x8*)&Buf2[g * 1160 + l15 * 72 + sub * 32 + quad * 8];
#pragma unroll
                for (int dt = 0; dt < 4; ++dt) {
                    const bf16* vp = Vbase + (size_t)(g * 64 + dt * 16 + l15) * 1024 +
                                     j0 + sub * 32 + quad * 8;
                    o[hh][dt] = MFMA_BF16(a, *(const bf16x8*)vp, o[hh][dt]);
                }
            }
        }
    }
#pragma unroll
    for (int hh = 0; hh < 2; ++hh) {
        int g = wv * 2 + hh;
#pragma unroll
        for (int dt = 0; dt < 4; ++dt)
#pragma unroll
            for (int r = 0; r < 4; ++r)
                atomicAdd(&out[(size_t)(b * 1024 + i0 + quad * 4 + r) * 1024 +
                               g * 64 + dt * 16 + l15], o[hh][dt][r]);
    }
}

extern "C" void kernel_launch(void* const* d_in, const int* in_sizes, int n_in,
                              void* d_out, int out_size, void* d_ws, size_t ws_size,
                              hipStream_t stream) {
    const float* x     = (const float*)d_in[0];
    const float* ctx   = (const float*)d_in[1];
    const float* Wq    = (const float*)d_in[2];
    const float* Wkv   = (const float*)d_in[3];
    const float* Wt    = (const float*)d_in[4];
    const float* gamma = (const float*)d_in[5];
    const float* beta  = (const float*)d_in[6];
    float* out = (float*)d_out;

    // ws layout (bf16 els): xb 4M | cb 4M | WqT 1M | WkvT 2M | Qb 4M | Kb 4M |
    //                       Vt 4M | L (64K fp32)  => ~46.5 MB
    bf16* xb   = (bf16*)d_ws;
    bf16* cb   = xb + (size_t)4 * 1024 * 1024;
    bf16* WqT  = cb + (size_t)4 * 1024 * 1024;
    bf16* WkvT = WqT + (size_t)1024 * 1024;
    bf16* Qb   = WkvT + (size_t)2048 * 1024;
    bf16* Kb   = Qb + (size_t)4 * 1024 * 1024;
    bf16* Vt   = Kb + (size_t)4 * 1024 * 1024;
    float* L   = (float*)(Vt + (size_t)4 * 1024 * 1024);

    hipMemsetAsync(L, 0, (size_t)4 * 16 * 1024 * sizeof(float), stream);
    hipMemsetAsync(out, 0, (size_t)out_size * sizeof(float), stream);

    cvt2_kernel<<<4096, 256, 0, stream>>>(x, ctx, xb, cb);
    trans2_kernel<<<dim3(64, 32, 2), 256, 0, stream>>>(Wq, Wkv, WqT, WkvT);
    gemm_all<<<dim3(24, 32), 256, 0, stream>>>(xb, cb, WqT, WkvT, Qb, Kb, Vt);
    denom_kernel<<<dim3(32, 4, 8), 256, 0, stream>>>(Qb, Kb, L);
    attn_kernel<<<dim3(64, 4, 2), 512, 0, stream>>>(Qb, Kb, Vt, L, Wt, gamma, beta, out);
}

// Round 4
// 365.592 us; speedup vs baseline: 1.1557x; 1.1557x over previous
//
#include <hip/hip_runtime.h>
#include <hip/hip_bf16.h>

typedef __bf16 bf16;
typedef bf16 bf16x2 __attribute__((ext_vector_type(2)));
typedef bf16 bf16x4 __attribute__((ext_vector_type(4)));
typedef bf16 bf16x8 __attribute__((ext_vector_type(8)));
typedef float floatx4 __attribute__((ext_vector_type(4)));

#define MFMA_BF16(a, b, c) __builtin_amdgcn_mfma_f32_16x16x32_bf16((a), (b), (c), 0, 0, 0)

// ---------------------------------------------------------------------------
// fp32 -> bf16 convert for BOTH x and ctx in one launch (8 els/thread).
// ---------------------------------------------------------------------------
__global__ __launch_bounds__(256) void cvt2_kernel(const float* __restrict__ x,
                                                   const float* __restrict__ ctx,
                                                   bf16* __restrict__ xb,
                                                   bf16* __restrict__ cb) {
    int idx = blockIdx.x * 256 + threadIdx.x;   // 0..1048575
    const float* in;
    bf16* out;
    int i;
    if (idx < 524288) { in = x; out = xb; i = idx; }
    else              { in = ctx; out = cb; i = idx - 524288; }
    const float* src = in + (size_t)i * 8;
    float4 f0 = *(const float4*)src;
    float4 f1 = *(const float4*)(src + 4);
    bf16x8 v = {(bf16)f0.x, (bf16)f0.y, (bf16)f0.z, (bf16)f0.w,
                (bf16)f1.x, (bf16)f1.y, (bf16)f1.z, (bf16)f1.w};
    *(bf16x8*)(out + (size_t)i * 8) = v;
}

// ---------------------------------------------------------------------------
// fp32 [1024][C] -> bf16 [C][1024] transpose for BOTH Wq (z=0) and Wkv (z=1).
// ---------------------------------------------------------------------------
__global__ __launch_bounds__(256) void trans2_kernel(const float* __restrict__ Wq,
                                                     const float* __restrict__ Wkv,
                                                     bf16* __restrict__ WqT,
                                                     bf16* __restrict__ WkvT) {
    const int z = blockIdx.z;
    if (z == 0 && blockIdx.x >= 32) return;
    const float* in = z ? Wkv : Wq;
    bf16* out = z ? WkvT : WqT;
    const int C = z ? 2048 : 1024, R = 1024;
    __shared__ float tile[32][33];
    const int t = threadIdx.x;
    const int r0 = blockIdx.y * 32, c0 = blockIdx.x * 32;
    int r = t >> 3, c4 = (t & 7) * 4;
    float4 v = *(const float4*)&in[(size_t)(r0 + r) * C + c0 + c4];
    tile[r][c4 + 0] = v.x; tile[r][c4 + 1] = v.y;
    tile[r][c4 + 2] = v.z; tile[r][c4 + 3] = v.w;
    __syncthreads();
    int rp = t >> 3, cp = (t & 7) * 4;
    bf16x4 w = {(bf16)tile[cp + 0][rp], (bf16)tile[cp + 1][rp],
                (bf16)tile[cp + 2][rp], (bf16)tile[cp + 3][rp]};
    *(bf16x4*)&out[(size_t)(c0 + rp) * R + r0 + cp] = w;
}

// ---------------------------------------------------------------------------
// Merged 128x128 GEMM: blockIdx.x<8 -> Q = xb @ WqT^T; else KV = cb @ WkvT^T.
// KV epilogue: n<1024 -> Kb[m][n]; n>=1024 -> Vt[b][h][d][j] directly (bf16x4).
// ---------------------------------------------------------------------------
__global__ __launch_bounds__(256) void gemm_all(const bf16* __restrict__ xb,
                                                const bf16* __restrict__ cb,
                                                const bf16* __restrict__ WqT,
                                                const bf16* __restrict__ WkvT,
                                                bf16* __restrict__ Qb,
                                                bf16* __restrict__ Kb,
                                                bf16* __restrict__ Vt) {
    __shared__ bf16 As[128 * 40];
    __shared__ bf16 Bs[128 * 40];
    const bool isQ = blockIdx.x < 8;
    const bf16* A = isQ ? xb : cb;
    const bf16* B = isQ ? WqT : WkvT;
    const int t = threadIdx.x;
    const int wv = t >> 6, lane = t & 63, quad = lane >> 4, l15 = lane & 15;
    const int wr = wv >> 1, wc = wv & 1;
    const int m0 = blockIdx.y * 128;
    const int n0 = (isQ ? blockIdx.x : blockIdx.x - 8) * 128;
    const int ra = t >> 1, kc = (t & 1) * 16;

    floatx4 acc[4][4] = {};

    for (int k0 = 0; k0 < 1024; k0 += 32) {
        bf16x8 a0 = *(const bf16x8*)&A[(size_t)(m0 + ra) * 1024 + k0 + kc];
        bf16x8 a1 = *(const bf16x8*)&A[(size_t)(m0 + ra) * 1024 + k0 + kc + 8];
        bf16x8 b0 = *(const bf16x8*)&B[(size_t)(n0 + ra) * 1024 + k0 + kc];
        bf16x8 b1 = *(const bf16x8*)&B[(size_t)(n0 + ra) * 1024 + k0 + kc + 8];
        __syncthreads();
        *(bf16x8*)&As[ra * 40 + kc] = a0;
        *(bf16x8*)&As[ra * 40 + kc + 8] = a1;
        *(bf16x8*)&Bs[ra * 40 + kc] = b0;
        *(bf16x8*)&Bs[ra * 40 + kc + 8] = b1;
        __syncthreads();
        bf16x8 af[4], bfr[4];
#pragma unroll
        for (int mt = 0; mt < 4; ++mt)
            af[mt] = *(bf16x8*)&As[(wr * 64 + mt * 16 + l15) * 40 + quad * 8];
#pragma unroll
        for (int nt = 0; nt < 4; ++nt)
            bfr[nt] = *(bf16x8*)&Bs[(wc * 64 + nt * 16 + l15) * 40 + quad * 8];
#pragma unroll
        for (int mt = 0; mt < 4; ++mt)
#pragma unroll
            for (int nt = 0; nt < 4; ++nt)
                acc[mt][nt] = MFMA_BF16(af[mt], bfr[nt], acc[mt][nt]);
    }
#pragma unroll
    for (int mt = 0; mt < 4; ++mt)
#pragma unroll
        for (int nt = 0; nt < 4; ++nt) {
            int mb = m0 + wr * 64 + mt * 16 + quad * 4;  // m for r=0 (4-aligned run)
            int n = n0 + wc * 64 + nt * 16 + l15;
            if (isQ) {
#pragma unroll
                for (int r = 0; r < 4; ++r)
                    Qb[(size_t)(mb + r) * 1024 + n] = (bf16)acc[mt][nt][r];
            } else if (n < 1024) {
#pragma unroll
                for (int r = 0; r < 4; ++r)
                    Kb[(size_t)(mb + r) * 1024 + n] = (bf16)acc[mt][nt][r];
            } else {
                int nn = n - 1024, h = nn >> 6, d = nn & 63;
                int bb = mb >> 10, j = mb & 1023;
                bf16x4 v4 = {(bf16)acc[mt][nt][0], (bf16)acc[mt][nt][1],
                             (bf16)acc[mt][nt][2], (bf16)acc[mt][nt][3]};
                *(bf16x4*)&Vt[(size_t)((bb * 16 + h) * 64 + d) * 1024 + j] = v4;
            }
        }
}

// ---------------------------------------------------------------------------
// Softmax denominators: L[b][h][i] = sum_j exp(q.k*scale).
// grid (i32=32, b=4, jsplit=8), 256 thr = 4 waves, 4 heads/wave.
// Head loop is OUTER so only one head's Q frags are live (no spills; the
// round-3 version spilled catastrophically under __launch_bounds__(256,4)).
// ---------------------------------------------------------------------------
__global__ __launch_bounds__(256) void denom_kernel(const bf16* __restrict__ Qb,
                                                    const bf16* __restrict__ Kb,
                                                    float* __restrict__ L) {
    const int t = threadIdx.x;
    const int wv = t >> 6, lane = t & 63, quad = lane >> 4, l15 = lane & 15;
    const int i0 = blockIdx.x * 32, b = blockIdx.y, jz = blockIdx.z;
    const float scale = 0.125f;
    const bf16* Kbase = Kb + (size_t)b * 1024 * 1024;

    for (int hh = 0; hh < 4; ++hh) {
        const int h = wv * 4 + hh;
        bf16x8 qa[2][2];
#pragma unroll
        for (int it = 0; it < 2; ++it) {
            const bf16* qp = Qb + (size_t)(b * 1024 + i0 + it * 16 + l15) * 1024 +
                             h * 64 + quad * 8;
            qa[it][0] = *(const bf16x8*)qp;
            qa[it][1] = *(const bf16x8*)(qp + 32);
        }
        floatx4 se[2] = {};
#pragma unroll
        for (int jt = 0; jt < 8; ++jt) {
            int j = jz * 128 + jt * 16 + l15;
            const bf16* kp = Kbase + (size_t)j * 1024 + h * 64 + quad * 8;
            bf16x8 k0 = *(const bf16x8*)kp;
            bf16x8 k1 = *(const bf16x8*)(kp + 32);
#pragma unroll
            for (int it = 0; it < 2; ++it) {
                floatx4 c = {0.f, 0.f, 0.f, 0.f};
                c = MFMA_BF16(qa[it][0], k0, c);
                c = MFMA_BF16(qa[it][1], k1, c);
#pragma unroll
                for (int r = 0; r < 4; ++r) se[it][r] += __expf(c[r] * scale);
            }
        }
#pragma unroll
        for (int it = 0; it < 2; ++it)
#pragma unroll
            for (int r = 0; r < 4; ++r) {
                float s = se[it][r];
                s += __shfl_xor(s, 1); s += __shfl_xor(s, 2);
                s += __shfl_xor(s, 4); s += __shfl_xor(s, 8);
                if (l15 == 0)
                    atomicAdd(&L[(size_t)(b * 16 + h) * 1024 + i0 + it * 16 +
                                 quad * 4 + r], s);
            }
    }
}

// ---------------------------------------------------------------------------
// Main fused attention. grid (i16=64, b=4, jsplit=4), 512 thr = 8 waves,
// 2 heads/wave, 32-wide j tiles (8 iters, 2 barriers each).
// LDS exactly 40 KB (Buf1 20K + Buf2 20K) -> 4 blocks/CU.
// (a) S (MFMA) -> w=exp*invl -> Buf1[point][h]
// (b) centered-Wt mix (MFMA, C[g][point]) + LN over g (2 shuffles) -> Buf2
//     (quads 2-3 read Buf1 at (quad&1)*8: a_wt[k>=16]=0 makes value irrelevant)
// (c) PV (MFMA, Vt B-frags from global). Partials atomicAdd'ed to out.
// ---------------------------------------------------------------------------
__global__ __launch_bounds__(512, 4) void attn_kernel(const bf16* __restrict__ Qb,
                                                      const bf16* __restrict__ Kb,
                                                      const bf16* __restrict__ Vt,
                                                      const float* __restrict__ L,
                                                      const float* __restrict__ Wt,
                                                      const float* __restrict__ gamma,
                                                      const float* __restrict__ beta,
                                                      float* __restrict__ out) {
    __shared__ bf16 Buf1[512 * 20];  // [point p=i*32+jl][16 h + 4 pad] = 20 KB
    __shared__ bf16 Buf2[16 * 640];  // [g][i*40 + jl]                  = 20 KB

    const int t = threadIdx.x;
    const int wv = t >> 6, lane = t & 63, quad = lane >> 4, l15 = lane & 15;
    const int i0 = blockIdx.x * 16, b = blockIdx.y, jz = blockIdx.z;
    const float scale = 0.125f;

    // A-frag of centered Wt^T: a_wt[jj] = Wt_c[k=quad*8+jj][g=l15], 0 for k>=16.
    bf16x8 a_wt;
#pragma unroll
    for (int jj = 0; jj < 8; ++jj) {
        int k = quad * 8 + jj;
        float v = 0.f;
        if (k < 16) {
            float s = 0.f;
            for (int g = 0; g < 16; ++g) s += Wt[k * 16 + g];
            v = Wt[k * 16 + l15] - s * 0.0625f;
        }
        a_wt[jj] = (bf16)v;
    }
    float gq[4], bq[4];
#pragma unroll
    for (int r = 0; r < 4; ++r) { gq[r] = gamma[quad * 4 + r]; bq[r] = beta[quad * 4 + r]; }

    bf16x8 qa[2][2];
    float invl[2][4];
#pragma unroll
    for (int hh = 0; hh < 2; ++hh) {
        int h = wv * 2 + hh;
        const bf16* qp = Qb + (size_t)(b * 1024 + i0 + l15) * 1024 + h * 64 + quad * 8;
        qa[hh][0] = *(const bf16x8*)qp;
        qa[hh][1] = *(const bf16x8*)(qp + 32);
#pragma unroll
        for (int r = 0; r < 4; ++r)
            invl[hh][r] = 1.f / L[(size_t)(b * 16 + h) * 1024 + i0 + quad * 4 + r];
    }

    const bf16* Kbase = Kb + (size_t)b * 1024 * 1024;
    const bf16* Vbase = Vt + (size_t)b * 16 * 64 * 1024;
    floatx4 o[2][4] = {};

    for (int jt = 0; jt < 8; ++jt) {
        const int j0 = jz * 256 + jt * 32;
        // (a) S -> w -> Buf1 (packed bf16x2 for the wave's head pair)
#pragma unroll
        for (int ns = 0; ns < 2; ++ns) {
            floatx4 cw[2];
#pragma unroll
            for (int hh = 0; hh < 2; ++hh) {
                int h = wv * 2 + hh;
                const bf16* kp = Kbase + (size_t)(j0 + ns * 16 + l15) * 1024 + h * 64 + quad * 8;
                floatx4 c = {0.f, 0.f, 0.f, 0.f};
                c = MFMA_BF16(qa[hh][0], *(const bf16x8*)kp, c);
                c = MFMA_BF16(qa[hh][1], *(const bf16x8*)(kp + 32), c);
                cw[hh] = c;
            }
#pragma unroll
            for (int r = 0; r < 4; ++r) {
                bf16x2 pk = {(bf16)(__expf(cw[0][r] * scale) * invl[0][r]),
                             (bf16)(__expf(cw[1][r] * scale) * invl[1][r])};
                *(bf16x2*)&Buf1[((quad * 4 + r) * 32 + ns * 16 + l15) * 20 + wv * 2] = pk;
            }
        }
        __syncthreads();
        // (b) mix (C[g][point]) + LN over g (mean exactly 0 by centering)
#pragma unroll
        for (int grp = 0; grp < 4; ++grp) {
            int gi = wv * 4 + grp, ig = gi >> 1, jb = (gi & 1) * 16;
            int p = ig * 32 + jb + l15;
            const bf16* src = &Buf1[p * 20 + (quad & 1) * 8];
            floatx4 c = {0.f, 0.f, 0.f, 0.f};
            c = MFMA_BF16(a_wt, *(const bf16x8*)src, c);
            float s2 = c[0] * c[0] + c[1] * c[1] + c[2] * c[2] + c[3] * c[3];
            s2 += __shfl_xor(s2, 16);
            s2 += __shfl_xor(s2, 32);
            float rs = rsqrtf(s2 * 0.0625f + 1e-5f);
#pragma unroll
            for (int r = 0; r < 4; ++r) {
                float w2 = c[r] * rs * gq[r] + bq[r];
                Buf2[(quad * 4 + r) * 640 + ig * 40 + jb + l15] = (bf16)w2;
            }
        }
        __syncthreads();
        // (c) PV: O[i][d] += w2[i][jl] * V[jl][d]
#pragma unroll
        for (int hh = 0; hh < 2; ++hh) {
            int g = wv * 2 + hh;
            bf16x8 a = *(bf16x8*)&Buf2[g * 640 + l15 * 40 + quad * 8];
#pragma unroll
            for (int dt = 0; dt < 4; ++dt) {
                const bf16* vp = Vbase + (size_t)(g * 64 + dt * 16 + l15) * 1024 +
                                 j0 + quad * 8;
                o[hh][dt] = MFMA_BF16(a, *(const bf16x8*)vp, o[hh][dt]);
            }
        }
    }
#pragma unroll
    for (int hh = 0; hh < 2; ++hh) {
        int g = wv * 2 + hh;
#pragma unroll
        for (int dt = 0; dt < 4; ++dt)
#pragma unroll
            for (int r = 0; r < 4; ++r)
                atomicAdd(&out[(size_t)(b * 1024 + i0 + quad * 4 + r) * 1024 +
                               g * 64 + dt * 16 + l15], o[hh][dt][r]);
    }
}

extern "C" void kernel_launch(void* const* d_in, const int* in_sizes, int n_in,
                              void* d_out, int out_size, void* d_ws, size_t ws_size,
                              hipStream_t stream) {
    const float* x     = (const float*)d_in[0];
    const float* ctx   = (const float*)d_in[1];
    const float* Wq    = (const float*)d_in[2];
    const float* Wkv   = (const float*)d_in[3];
    const float* Wt    = (const float*)d_in[4];
    const float* gamma = (const float*)d_in[5];
    const float* beta  = (const float*)d_in[6];
    float* out = (float*)d_out;

    // ws layout (bf16 els): xb 4M | cb 4M | WqT 1M | WkvT 2M | Qb 4M | Kb 4M |
    //                       Vt 4M | L (64K fp32)  => ~46.5 MB
    bf16* xb   = (bf16*)d_ws;
    bf16* cb   = xb + (size_t)4 * 1024 * 1024;
    bf16* WqT  = cb + (size_t)4 * 1024 * 1024;
    bf16* WkvT = WqT + (size_t)1024 * 1024;
    bf16* Qb   = WkvT + (size_t)2048 * 1024;
    bf16* Kb   = Qb + (size_t)4 * 1024 * 1024;
    bf16* Vt   = Kb + (size_t)4 * 1024 * 1024;
    float* L   = (float*)(Vt + (size_t)4 * 1024 * 1024);

    hipMemsetAsync(L, 0, (size_t)4 * 16 * 1024 * sizeof(float), stream);
    hipMemsetAsync(out, 0, (size_t)out_size * sizeof(float), stream);

    cvt2_kernel<<<4096, 256, 0, stream>>>(x, ctx, xb, cb);
    trans2_kernel<<<dim3(64, 32, 2), 256, 0, stream>>>(Wq, Wkv, WqT, WkvT);
    gemm_all<<<dim3(24, 32), 256, 0, stream>>>(xb, cb, WqT, WkvT, Qb, Kb, Vt);
    denom_kernel<<<dim3(32, 4, 8), 256, 0, stream>>>(Qb, Kb, L);
    attn_kernel<<<dim3(64, 4, 4), 512, 0, stream>>>(Qb, Kb, Vt, L, Wt, gamma, beta, out);
}